// Round 1
// baseline (390.731 us; speedup 1.0000x reference)
//
#include <hip/hip_runtime.h>

// MSA column global attention, MI355X gfx950.
// B=1, N=512, L=1024, D=64, NH=8, DH=8.
// K1: LN + k,v (bf16 ws) + xsum partials      (reads msa 134MB)
// K2: q = xsum@Wq/512*scale; softmax over n; attn_out[1024][64] f32
// K3: LN again + gate=sigmoid(x@Wg+bg) via MFMA; out=(gate*a)@Wo+bo via MFMA

#define NN 512
#define LL 1024
#define DD 64

typedef float fx4 __attribute__((ext_vector_type(4)));
typedef unsigned int ux2 __attribute__((ext_vector_type(2)));
typedef short bh8 __attribute__((ext_vector_type(8)));   // 8 bf16 (4 VGPRs) MFMA frag

__device__ __forceinline__ unsigned short f2bf(float f) {
  union { float f; unsigned int u; } c; c.f = f;
  unsigned int u = c.u;
  u += 0x7fffu + ((u >> 16) & 1u);          // RNE
  return (unsigned short)(u >> 16);
}
__device__ __forceinline__ float bf2f(unsigned short b) {
  union { unsigned int u; float f; } c; c.u = ((unsigned int)b) << 16;
  return c.f;
}

// ---------------------------------------------------------------- K1
// grid 1024, block 256. block b: l-quad = (b>>2)*4, n-range = (b&3)*128.
// wave w covers n-subrange of 32; lane = p*16+f: p = l-offset (4 l's), f = feat group (4 feats).
__global__ __launch_bounds__(256) void k1_kernel(
    const float* __restrict__ msa, const float* __restrict__ lnw,
    const float* __restrict__ lnb, const float* __restrict__ Wk,
    const float* __restrict__ Wv, unsigned short* __restrict__ wsK,
    unsigned short* __restrict__ wsV, float* __restrict__ wsXsumP)
{
  const int tid = threadIdx.x;
  const int w = tid >> 6;
  const int lane = tid & 63;
  const int p = lane >> 4;
  const int f = lane & 15;
  const int lq = blockIdx.x >> 2;
  const int nr = blockIdx.x & 3;
  const int l = (lq << 2) + p;
  const int n0 = (nr << 7) + (w << 5);

  fx4 lw = *(const fx4*)(lnw + 4 * f);
  fx4 lb = *(const fx4*)(lnb + 4 * f);

  float wk[4][8], wvv[4][8];
#pragma unroll
  for (int i = 0; i < 4; ++i)
#pragma unroll
    for (int j = 0; j < 8; ++j) {
      wk[i][j]  = Wk[(4 * f + i) * 8 + j];
      wvv[i][j] = Wv[(4 * f + i) * 8 + j];
    }

  fx4 xs = {0.f, 0.f, 0.f, 0.f};

  for (int it = 0; it < 32; ++it) {
    int n = n0 + it;
    fx4 x = *(const fx4*)(msa + ((size_t)n * LL + l) * DD + 4 * f);
    float s  = x.x + x.y + x.z + x.w;
    float ss = x.x * x.x + x.y * x.y + x.z * x.z + x.w * x.w;
#pragma unroll
    for (int m = 1; m <= 8; m <<= 1) {
      s  += __shfl_xor(s, m);
      ss += __shfl_xor(ss, m);
    }
    float mu  = s * (1.f / 64.f);
    float var = ss * (1.f / 64.f) - mu * mu;
    float rs  = rsqrtf(var + 1e-5f);
    fx4 xn;
    xn.x = (x.x - mu) * rs * lw.x + lb.x;
    xn.y = (x.y - mu) * rs * lw.y + lb.y;
    xn.z = (x.z - mu) * rs * lw.z + lb.z;
    xn.w = (x.w - mu) * rs * lw.w + lb.w;
    xs += xn;

    float kp[8], vp[8];
#pragma unroll
    for (int j = 0; j < 8; ++j) {
      kp[j] = xn.x * wk[0][j];
      kp[j] = fmaf(xn.y, wk[1][j], kp[j]);
      kp[j] = fmaf(xn.z, wk[2][j], kp[j]);
      kp[j] = fmaf(xn.w, wk[3][j], kp[j]);
      vp[j] = xn.x * wvv[0][j];
      vp[j] = fmaf(xn.y, wvv[1][j], vp[j]);
      vp[j] = fmaf(xn.z, wvv[2][j], vp[j]);
      vp[j] = fmaf(xn.w, wvv[3][j], vp[j]);
    }
#pragma unroll
    for (int m = 1; m <= 8; m <<= 1) {
#pragma unroll
      for (int j = 0; j < 8; ++j) {
        kp[j] += __shfl_xor(kp[j], m);
        vp[j] += __shfl_xor(vp[j], m);
      }
    }
    float kv = kp[0], vv2 = vp[0];
#pragma unroll
    for (int j = 1; j < 8; ++j) {
      if (f == j) { kv = kp[j]; vv2 = vp[j]; }
    }
    if (f < 8) {
      size_t off = ((size_t)l * NN + n) * 8 + f;
      wsK[off] = f2bf(kv);
      wsV[off] = f2bf(vv2);
    }
  }

  __shared__ float xred[4][4][64];
  *(fx4*)&xred[w][p][4 * f] = xs;
  __syncthreads();
  int pp = tid >> 6, ff = tid & 63;
  float v4 = xred[0][pp][ff] + xred[1][pp][ff] + xred[2][pp][ff] + xred[3][pp][ff];
  wsXsumP[(size_t)nr * (LL * 64) + ((lq << 2) + pp) * 64 + ff] = v4;
}

// ---------------------------------------------------------------- K2
// grid 256, block 256. wave w handles l = blk*4 + w. lane <-> n (8 chunks of 64).
__global__ __launch_bounds__(256) void k2_kernel(
    const float* __restrict__ Wq, const float* __restrict__ wsXsumP,
    const unsigned short* __restrict__ wsK, const unsigned short* __restrict__ wsV,
    float* __restrict__ wsAttn)
{
  __shared__ float red[4][32][65];
  const int tid = threadIdx.x;
  const int w = tid >> 6;
  const int lane = tid & 63;
  const int l = (blockIdx.x << 2) + w;

  // xsum (4 partials) and q projection: lane j computes q_j via shfl broadcast
  float xl = wsXsumP[l * 64 + lane]
           + wsXsumP[1 * (LL * 64) + l * 64 + lane]
           + wsXsumP[2 * (LL * 64) + l * 64 + lane]
           + wsXsumP[3 * (LL * 64) + l * 64 + lane];
  float acc = 0.f;
#pragma unroll
  for (int d = 0; d < 64; ++d) {
    float xd = __shfl(xl, d);
    acc = fmaf(xd, Wq[d * 64 + lane], acc);
  }
  float qq = acc * (1.f / 512.f) * 0.35355339059327373f;  // mean over N, * 1/sqrt(8)
  float qv[64];
#pragma unroll
  for (int j = 0; j < 64; ++j) qv[j] = __shfl(qq, j);

  // scores s[c][h], n = c*64 + lane
  float s[8][8];
  const unsigned short* kb = wsK + (size_t)l * NN * 8;
#pragma unroll
  for (int c = 0; c < 8; ++c) {
    int n = (c << 6) + lane;
    uint4 kr = *(const uint4*)(kb + n * 8);
    float kf[8];
    kf[0] = bf2f((unsigned short)(kr.x & 0xffffu)); kf[1] = bf2f((unsigned short)(kr.x >> 16));
    kf[2] = bf2f((unsigned short)(kr.y & 0xffffu)); kf[3] = bf2f((unsigned short)(kr.y >> 16));
    kf[4] = bf2f((unsigned short)(kr.z & 0xffffu)); kf[5] = bf2f((unsigned short)(kr.z >> 16));
    kf[6] = bf2f((unsigned short)(kr.w & 0xffffu)); kf[7] = bf2f((unsigned short)(kr.w >> 16));
#pragma unroll
    for (int h = 0; h < 8; ++h) {
      float t = 0.f;
#pragma unroll
      for (int dh = 0; dh < 8; ++dh) t = fmaf(qv[h * 8 + dh], kf[dh], t);
      s[c][h] = t;
    }
  }

  // softmax over n (per h): max, exp, sum
  float mx[8];
#pragma unroll
  for (int h = 0; h < 8; ++h) mx[h] = s[0][h];
#pragma unroll
  for (int c = 1; c < 8; ++c)
#pragma unroll
    for (int h = 0; h < 8; ++h) mx[h] = fmaxf(mx[h], s[c][h]);
#pragma unroll
  for (int m = 1; m < 64; m <<= 1)
#pragma unroll
    for (int h = 0; h < 8; ++h) mx[h] = fmaxf(mx[h], __shfl_xor(mx[h], m));

  float den[8] = {0.f, 0.f, 0.f, 0.f, 0.f, 0.f, 0.f, 0.f};
#pragma unroll
  for (int c = 0; c < 8; ++c)
#pragma unroll
    for (int h = 0; h < 8; ++h) { s[c][h] = __expf(s[c][h] - mx[h]); den[h] += s[c][h]; }
#pragma unroll
  for (int m = 1; m < 64; m <<= 1)
#pragma unroll
    for (int h = 0; h < 8; ++h) den[h] += __shfl_xor(den[h], m);
  float rden[8];
#pragma unroll
  for (int h = 0; h < 8; ++h) rden[h] = 1.f / den[h];

  // PV: per-lane partials oa[h*8+dh]
  float oa[64];
#pragma unroll
  for (int j = 0; j < 64; ++j) oa[j] = 0.f;
  const unsigned short* vb = wsV + (size_t)l * NN * 8;
#pragma unroll
  for (int c = 0; c < 8; ++c) {
    int n = (c << 6) + lane;
    uint4 vr = *(const uint4*)(vb + n * 8);
    float vf[8];
    vf[0] = bf2f((unsigned short)(vr.x & 0xffffu)); vf[1] = bf2f((unsigned short)(vr.x >> 16));
    vf[2] = bf2f((unsigned short)(vr.y & 0xffffu)); vf[3] = bf2f((unsigned short)(vr.y >> 16));
    vf[4] = bf2f((unsigned short)(vr.z & 0xffffu)); vf[5] = bf2f((unsigned short)(vr.z >> 16));
    vf[6] = bf2f((unsigned short)(vr.w & 0xffffu)); vf[7] = bf2f((unsigned short)(vr.w >> 16));
#pragma unroll
    for (int h = 0; h < 8; ++h) {
      float pch = s[c][h];
#pragma unroll
      for (int dh = 0; dh < 8; ++dh) oa[h * 8 + dh] = fmaf(pch, vf[dh], oa[h * 8 + dh]);
    }
  }
#pragma unroll
  for (int h = 0; h < 8; ++h)
#pragma unroll
    for (int dh = 0; dh < 8; ++dh) oa[h * 8 + dh] *= rden[h];

  // cross-lane reduce via LDS (stride 65 -> conflict-free), 2 rounds of 32 values
  float o0 = 0.f, o1 = 0.f;
#pragma unroll
  for (int j = 0; j < 32; ++j) red[w][j][lane] = oa[j];
#pragma unroll
  for (int src = 0; src < 64; ++src) o0 += red[w][lane & 31][src];
#pragma unroll
  for (int j = 0; j < 32; ++j) red[w][j][lane] = oa[32 + j];
#pragma unroll
  for (int src = 0; src < 64; ++src) o1 += red[w][lane & 31][src];
  if (lane < 32) {
    wsAttn[l * 64 + lane] = o0;
    wsAttn[l * 64 + 32 + lane] = o1;
  }
}

// ---------------------------------------------------------------- K3
// grid 2048, block 256. Block covers 256 consecutive flat positions (same n, l-range 256).
// Stage LN'd x as bf16 in LDS (XOR-swizzled 16B granules), then per 16-row tile:
//   z = x@Wg (MFMA) ; g = sigmoid(z+bg) ; y = g*attn ; out = y@Wo (MFMA) + bo.
__global__ __launch_bounds__(256) void k3_kernel(
    const float* __restrict__ msa, const float* __restrict__ lnw,
    const float* __restrict__ lnb, const float* __restrict__ Wg,
    const float* __restrict__ bg, const float* __restrict__ Wo,
    const float* __restrict__ bo, const float* __restrict__ wsAttn,
    float* __restrict__ outp)
{
  __shared__ unsigned short xt[256][64];   // 32 KB, swizzled
  __shared__ unsigned short wgT[64][64];   // 8 KB, WgT[j][d] = Wg[d][j], swizzled
  __shared__ unsigned short woT[64][64];   // 8 KB
  __shared__ unsigned short yt[4][16][64]; // 8 KB, per-wave y tile, swizzled

  const int tid = threadIdx.x;
  const int w = tid >> 6;
  const int lane = tid & 63;

  // stage transposed bf16 weights (reads L1/L2-cached, writes conflict-free)
  {
    int d = tid & 63;
    int jg = tid >> 6;
#pragma unroll
    for (int j0 = 0; j0 < 16; ++j0) {
      int j = (j0 << 2) + jg;
      int gs = ((d >> 3) ^ (j & 7)) * 8 + (d & 7);
      wgT[j][gs] = f2bf(Wg[d * 64 + j]);
      woT[j][gs] = f2bf(Wo[d * 64 + j]);
    }
  }

  // stage x: LN with 16-lane groups, coalesced 1KB/wave loads
  const int ps = lane >> 4, f = lane & 15;
  fx4 lw = *(const fx4*)(lnw + 4 * f);
  fx4 lb = *(const fx4*)(lnb + 4 * f);
  const size_t gbase = (size_t)blockIdx.x * 256;
  for (int it = 0; it < 16; ++it) {
    int posL = (w << 6) + (it << 2) + ps;
    size_t gpos = gbase + posL;
    fx4 x = *(const fx4*)(msa + gpos * 64 + 4 * f);
    float sv  = x.x + x.y + x.z + x.w;
    float ssv = x.x * x.x + x.y * x.y + x.z * x.z + x.w * x.w;
#pragma unroll
    for (int m = 1; m <= 8; m <<= 1) { sv += __shfl_xor(sv, m); ssv += __shfl_xor(ssv, m); }
    float mu  = sv * (1.f / 64.f);
    float var = ssv * (1.f / 64.f) - mu * mu;
    float rs  = rsqrtf(var + 1e-5f);
    float x0 = (x.x - mu) * rs * lw.x + lb.x;
    float x1 = (x.y - mu) * rs * lw.y + lb.y;
    float x2 = (x.z - mu) * rs * lw.z + lb.z;
    float x3 = (x.w - mu) * rs * lw.w + lb.w;
    unsigned int u0 = (unsigned int)f2bf(x0) | ((unsigned int)f2bf(x1) << 16);
    unsigned int u1 = (unsigned int)f2bf(x2) | ((unsigned int)f2bf(x3) << 16);
    int gsw = (((f >> 1) ^ (posL & 7)) * 8) + (f & 1) * 4;
    ux2 uu = {u0, u1};
    *(ux2*)&xt[posL][gsw] = uu;
  }
  __syncthreads();

  // MFMA phase: A row = lane&15, k-group = lane>>4 ; C/D: col=lane&15, row=(lane>>4)*4+reg
  const int c  = lane & 15;
  const int kg = lane >> 4;
  bh8 bgf[4][2], bof[4][2];
  float bgv[4], bov[4];
#pragma unroll
  for (int nt = 0; nt < 4; ++nt) {
    int col = (nt << 4) + c;
    int sw = col & 7;
    bgf[nt][0] = *(const bh8*)&wgT[col][((kg    ) ^ sw) * 8];
    bgf[nt][1] = *(const bh8*)&wgT[col][((kg + 4) ^ sw) * 8];
    bof[nt][0] = *(const bh8*)&woT[col][((kg    ) ^ sw) * 8];
    bof[nt][1] = *(const bh8*)&woT[col][((kg + 4) ^ sw) * 8];
    bgv[nt] = bg[col];
    bov[nt] = bo[col];
  }

  const int lbase = (int)(gbase & (LL - 1));
  fx4 zero = {0.f, 0.f, 0.f, 0.f};
#pragma unroll
  for (int mt = 0; mt < 4; ++mt) {
    int r0 = (w << 6) + (mt << 4);
    int rowA = r0 + c;
    int swA = rowA & 7;
    bh8 a0 = *(const bh8*)&xt[rowA][((kg    ) ^ swA) * 8];
    bh8 a1 = *(const bh8*)&xt[rowA][((kg + 4) ^ swA) * 8];
    fx4 ag[4];
#pragma unroll
    for (int nt = 0; nt < 4; ++nt) {
      fx4 t = __builtin_amdgcn_mfma_f32_16x16x32_bf16(a0, bgf[nt][0], zero, 0, 0, 0);
      ag[nt] = __builtin_amdgcn_mfma_f32_16x16x32_bf16(a1, bgf[nt][1], t, 0, 0, 0);
    }
    // gate epilogue -> yt (bf16)
#pragma unroll
    for (int nt = 0; nt < 4; ++nt) {
      int col = (nt << 4) + c;
#pragma unroll
      for (int r = 0; r < 4; ++r) {
        int rloc = (kg << 2) + r;
        float z = ag[nt][r] + bgv[nt];
        float g = 1.f / (1.f + __expf(-z));
        int lidx = lbase + r0 + rloc;
        float a = wsAttn[lidx * 64 + col];
        float y = g * a;
        int gy = (((col >> 3) ^ (rloc & 7)) * 8) + (col & 7);
        yt[w][rloc][gy] = f2bf(y);
      }
    }
    // second GEMM: out = y @ Wo
    int swY = c & 7;
    bh8 y0 = *(const bh8*)&yt[w][c][((kg    ) ^ swY) * 8];
    bh8 y1 = *(const bh8*)&yt[w][c][((kg + 4) ^ swY) * 8];
    fx4 ao[4];
#pragma unroll
    for (int nt = 0; nt < 4; ++nt) {
      fx4 t = __builtin_amdgcn_mfma_f32_16x16x32_bf16(y0, bof[nt][0], zero, 0, 0, 0);
      ao[nt] = __builtin_amdgcn_mfma_f32_16x16x32_bf16(y1, bof[nt][1], t, 0, 0, 0);
    }
#pragma unroll
    for (int nt = 0; nt < 4; ++nt) {
      int col = (nt << 4) + c;
#pragma unroll
      for (int r = 0; r < 4; ++r) {
        int rloc = (kg << 2) + r;
        size_t gpos = gbase + r0 + rloc;
        outp[gpos * 64 + col] = ao[nt][r] + bov[nt];
      }
    }
  }
}

// ---------------------------------------------------------------- launcher
extern "C" void kernel_launch(void* const* d_in, const int* in_sizes, int n_in,
                              void* d_out, int out_size, void* d_ws, size_t ws_size,
                              hipStream_t stream) {
  const float* msa = (const float*)d_in[0];
  const float* lnw = (const float*)d_in[1];
  const float* lnb = (const float*)d_in[2];
  const float* Wq  = (const float*)d_in[3];
  const float* Wk  = (const float*)d_in[4];
  const float* Wv  = (const float*)d_in[5];
  const float* Wg  = (const float*)d_in[6];
  const float* bg  = (const float*)d_in[7];
  const float* Wo  = (const float*)d_in[8];
  const float* bo  = (const float*)d_in[9];
  float* outp = (float*)d_out;

  char* ws = (char*)d_ws;
  unsigned short* wsK    = (unsigned short*)ws;                    //  8,388,608 B
  unsigned short* wsV    = (unsigned short*)(ws + 8388608);        //  8,388,608 B
  float*          wsXsum = (float*)(ws + 16777216);                //  1,048,576 B (4 partials)
  float*          wsAttn = (float*)(ws + 17825792);                //    262,144 B

  k1_kernel<<<dim3(1024), dim3(256), 0, stream>>>(msa, lnw, lnb, Wk, Wv, wsK, wsV, wsXsum);
  k2_kernel<<<dim3(256),  dim3(256), 0, stream>>>(Wq, wsXsum, wsK, wsV, wsAttn);
  k3_kernel<<<dim3(2048), dim3(256), 0, stream>>>(msa, lnw, lnb, Wg, bg, Wo, bo, wsAttn, outp);
}

// Round 3
// 354.037 us; speedup vs baseline: 1.1036x; 1.1036x over previous
//
#include <hip/hip_runtime.h>

// MSA column global attention, MI355X gfx950.
// B=1, N=512, L=1024, D=64, NH=8, DH=8.
// K1: LN + k|v via MFMA (bf16 ws, interleaved) + xsum partials (reads msa 134MB)
// K2: q = xsum@Wq/512*scale; softmax over n per (l,h); attn_out[1024][64] f32
// K3: LN again + gate=sigmoid(x@Wg+bg) via MFMA; out=(gate*a)@Wo+bo via MFMA

#define NN 512
#define LL 1024

typedef float fx4 __attribute__((ext_vector_type(4)));
typedef unsigned int ux2 __attribute__((ext_vector_type(2)));
typedef short bh8 __attribute__((ext_vector_type(8)));   // 8 bf16 (4 VGPRs) MFMA frag

static __device__ __forceinline__ unsigned short f2bf(float f) {
  union { float f; unsigned int u; } c; c.f = f;
  unsigned int u = c.u;
  u += 0x7fffu + ((u >> 16) & 1u);          // RNE
  return (unsigned short)(u >> 16);
}
static __device__ __forceinline__ float bf2f(unsigned short b) {
  union { unsigned int u; float f; } c; c.u = ((unsigned int)b) << 16;
  return c.f;
}

// ---------------------------------------------------------------- K1
// grid 2048 = 32 n-chunks x 64 l-chunks; block 256 (4 waves).
// Wave w handles n = n0 + w*4 .. +4 (one 16-row l-tile per n, MFMA per tile).
__global__ __launch_bounds__(256) void k1_kernel(
    const float* __restrict__ msa, const float* __restrict__ lnw,
    const float* __restrict__ lnb, const float* __restrict__ Wk,
    const float* __restrict__ Wv, unsigned short* __restrict__ wsKV,
    float* __restrict__ wsXsumP)
{
  __shared__ unsigned short wkv[16][64];        // 2 KB  B^T swizzled (k cols 0-7, v cols 8-15)
  __shared__ unsigned short xt[4][2][16][64];   // 16 KB per-wave double-buffered x tile
  __shared__ float xsred[4][16][64];            // 16 KB per-wave xsum partials

  const int tid  = threadIdx.x;
  const int w    = tid >> 6;
  const int lane = tid & 63;
  const int p    = lane >> 4;
  const int f    = lane & 15;
  const int nb   = blockIdx.x >> 6;   // 0..31
  const int lbk  = blockIdx.x & 63;   // 0..63
  const int n0   = nb << 4;
  const int l0   = lbk << 4;

  // stage [Wk|Wv]^T bf16, granule-swizzled by col
  {
    const int col = tid & 15;
    const int d0  = (tid >> 4) << 2;
    const float* Wsrc = (col < 8) ? Wk : Wv;
    const int cc = col & 7;
#pragma unroll
    for (int dd = 0; dd < 4; ++dd) {
      const int d  = d0 + dd;
      const int gs = (((d >> 3) ^ (col & 7)) << 3) + (d & 7);
      wkv[col][gs] = f2bf(Wsrc[d * 8 + cc]);
    }
  }
  __syncthreads();

  const int c  = lane & 15;
  const int kg = lane >> 4;
  const bh8 wb0 = *(const bh8*)&wkv[c][((kg    ) ^ (c & 7)) << 3];
  const bh8 wb1 = *(const bh8*)&wkv[c][((kg + 4) ^ (c & 7)) << 3];

  const fx4 lwv = *(const fx4*)(lnw + 4 * f);
  const fx4 lbv = *(const fx4*)(lnb + 4 * f);
  const fx4 zero = {0.f, 0.f, 0.f, 0.f};

  fx4 xs4[4];
#pragma unroll
  for (int jq = 0; jq < 4; ++jq) { xs4[jq].x = 0.f; xs4[jq].y = 0.f; xs4[jq].z = 0.f; xs4[jq].w = 0.f; }

#pragma unroll
  for (int it = 0; it < 4; ++it) {
    const int i = (w << 2) + it;
    const int n = n0 + i;
    const int bufp = it & 1;
#pragma unroll
    for (int jq = 0; jq < 4; ++jq) {
      const int j = (jq << 2) + p;
      fx4 x = *(const fx4*)(msa + ((size_t)n * LL + (l0 + j)) * 64 + 4 * f);
      float s  = x.x + x.y + x.z + x.w;
      float ss = x.x * x.x + x.y * x.y + x.z * x.z + x.w * x.w;
#pragma unroll
      for (int m = 1; m <= 8; m <<= 1) { s += __shfl_xor(s, m); ss += __shfl_xor(ss, m); }
      const float mu  = s * (1.f / 64.f);
      const float var = ss * (1.f / 64.f) - mu * mu;
      const float rs  = rsqrtf(var + 1e-5f);
      fx4 xn;
      xn.x = (x.x - mu) * rs * lwv.x + lbv.x;
      xn.y = (x.y - mu) * rs * lwv.y + lbv.y;
      xn.z = (x.z - mu) * rs * lwv.z + lbv.z;
      xn.w = (x.w - mu) * rs * lwv.w + lbv.w;
      xs4[jq] += xn;
      const unsigned int u0 = (unsigned int)f2bf(xn.x) | ((unsigned int)f2bf(xn.y) << 16);
      const unsigned int u1 = (unsigned int)f2bf(xn.z) | ((unsigned int)f2bf(xn.w) << 16);
      const int gsw = (((f >> 1) ^ (j & 7)) << 3) + ((f & 1) << 2);
      ux2 uu = {u0, u1};
      *(ux2*)&xt[w][bufp][j][gsw] = uu;
    }
    // A-frags: row = c, feat granules kg / kg+4 (swizzle-corrected)
    bh8 a0 = *(const bh8*)&xt[w][bufp][c][((kg    ) ^ (c & 7)) << 3];
    bh8 a1 = *(const bh8*)&xt[w][bufp][c][((kg + 4) ^ (c & 7)) << 3];
    fx4 kv = __builtin_amdgcn_mfma_f32_16x16x32_bf16(a0, wb0, zero, 0, 0, 0);
    kv = __builtin_amdgcn_mfma_f32_16x16x32_bf16(a1, wb1, kv, 0, 0, 0);
    // C/D: col = c (k:0-7, v:8-15), row = kg*4+r -> l = l0 + row
#pragma unroll
    for (int r = 0; r < 4; ++r) {
      const int l = l0 + (kg << 2) + r;
      wsKV[((size_t)l * NN + n) * 16 + c] = f2bf(kv[r]);
    }
  }

  // block xsum partial: lane (p,f) holds j = jq*4+p
#pragma unroll
  for (int jq = 0; jq < 4; ++jq)
    *(fx4*)&xsred[w][(jq << 2) + p][4 * f] = xs4[jq];
  __syncthreads();
  {
    const int j  = tid >> 4;
    const int fq = tid & 15;
    fx4 a  = *(const fx4*)&xsred[0][j][4 * fq];
    fx4 b  = *(const fx4*)&xsred[1][j][4 * fq];
    fx4 c2 = *(const fx4*)&xsred[2][j][4 * fq];
    fx4 d  = *(const fx4*)&xsred[3][j][4 * fq];
    fx4 ssum = (a + b) + (c2 + d);
    *(fx4*)(wsXsumP + ((size_t)nb * LL + (l0 + j)) * 64 + 4 * fq) = ssum;
  }
}

// ---------------------------------------------------------------- K2
// grid 1024 (one l per block), block 512 (8 waves = 8 heads). No big reg arrays.
__global__ __launch_bounds__(512) void k2_kernel(
    const float* __restrict__ Wq, const float* __restrict__ wsXsumP,
    const unsigned short* __restrict__ wsKV, float* __restrict__ wsAttn)
{
  __shared__ float xsp[8][64];
  __shared__ float xsum[64];
  const int tid = threadIdx.x;
  const int l   = blockIdx.x;

  {
    const int d  = tid & 63;
    const int c0 = tid >> 6;
    float acc = 0.f;
#pragma unroll
    for (int m = 0; m < 4; ++m)
      acc += wsXsumP[((size_t)(c0 + (m << 3)) * LL + l) * 64 + d];
    xsp[c0][d] = acc;
  }
  __syncthreads();
  if (tid < 64) {
    float a = 0.f;
#pragma unroll
    for (int cg = 0; cg < 8; ++cg) a += xsp[cg][tid];
    xsum[tid] = a;
  }
  __syncthreads();

  const int h    = tid >> 6;
  const int lane = tid & 63;
  const int dh   = lane & 7;
  const int g    = lane >> 3;

  // q[h][dh]: 8-lane-parallel partial dot + xor reduce over g-bits
  float qp = 0.f;
#pragma unroll
  for (int k = 0; k < 8; ++k) {
    const int d = (g << 3) + k;
    qp = fmaf(xsum[d], Wq[d * 64 + (h << 3) + dh], qp);
  }
  qp += __shfl_xor(qp, 8);
  qp += __shfl_xor(qp, 16);
  qp += __shfl_xor(qp, 32);
  const float qsc = qp * (0.35355339059327373f / 512.f);  // mean over N, * 1/sqrt(8)
  float qv[8];
#pragma unroll
  for (int j2 = 0; j2 < 8; ++j2) qv[j2] = __shfl(qsc, j2);

  // lane owns n = cc*64 + lane
  const unsigned short* kvb = wsKV + (size_t)l * NN * 16;
  float s[8];
#pragma unroll
  for (int cc = 0; cc < 8; ++cc) {
    const int n = (cc << 6) + lane;
    uint4 kr = *(const uint4*)(kvb + (size_t)n * 16);
    float t;
    t = qv[0] * bf2f((unsigned short)(kr.x & 0xffffu));
    t = fmaf(qv[1], bf2f((unsigned short)(kr.x >> 16)), t);
    t = fmaf(qv[2], bf2f((unsigned short)(kr.y & 0xffffu)), t);
    t = fmaf(qv[3], bf2f((unsigned short)(kr.y >> 16)), t);
    t = fmaf(qv[4], bf2f((unsigned short)(kr.z & 0xffffu)), t);
    t = fmaf(qv[5], bf2f((unsigned short)(kr.z >> 16)), t);
    t = fmaf(qv[6], bf2f((unsigned short)(kr.w & 0xffffu)), t);
    t = fmaf(qv[7], bf2f((unsigned short)(kr.w >> 16)), t);
    s[cc] = t;
  }
  float mx = s[0];
#pragma unroll
  for (int cc = 1; cc < 8; ++cc) mx = fmaxf(mx, s[cc]);
#pragma unroll
  for (int m = 1; m < 64; m <<= 1) mx = fmaxf(mx, __shfl_xor(mx, m));
  float den = 0.f;
#pragma unroll
  for (int cc = 0; cc < 8; ++cc) { s[cc] = __expf(s[cc] - mx); den += s[cc]; }
#pragma unroll
  for (int m = 1; m < 64; m <<= 1) den += __shfl_xor(den, m);
  const float rden = 1.f / den;

  float oa[8];
#pragma unroll
  for (int j2 = 0; j2 < 8; ++j2) oa[j2] = 0.f;
#pragma unroll
  for (int cc = 0; cc < 8; ++cc) {
    const int n = (cc << 6) + lane;
    uint4 vr = *(const uint4*)(kvb + (size_t)n * 16 + 8);
    const float pch = s[cc];
    oa[0] = fmaf(pch, bf2f((unsigned short)(vr.x & 0xffffu)), oa[0]);
    oa[1] = fmaf(pch, bf2f((unsigned short)(vr.x >> 16)), oa[1]);
    oa[2] = fmaf(pch, bf2f((unsigned short)(vr.y & 0xffffu)), oa[2]);
    oa[3] = fmaf(pch, bf2f((unsigned short)(vr.y >> 16)), oa[3]);
    oa[4] = fmaf(pch, bf2f((unsigned short)(vr.z & 0xffffu)), oa[4]);
    oa[5] = fmaf(pch, bf2f((unsigned short)(vr.z >> 16)), oa[5]);
    oa[6] = fmaf(pch, bf2f((unsigned short)(vr.w & 0xffffu)), oa[6]);
    oa[7] = fmaf(pch, bf2f((unsigned short)(vr.w >> 16)), oa[7]);
  }
#pragma unroll
  for (int j2 = 0; j2 < 8; ++j2) oa[j2] *= rden;
#pragma unroll
  for (int m = 1; m < 64; m <<= 1)
#pragma unroll
    for (int j2 = 0; j2 < 8; ++j2) oa[j2] += __shfl_xor(oa[j2], m);
  if (lane < 8) {
    float ov = oa[0];
#pragma unroll
    for (int j2 = 1; j2 < 8; ++j2) if (lane == j2) ov = oa[j2];
    wsAttn[l * 64 + (h << 3) + lane] = ov;
  }
}

// ---------------------------------------------------------------- K3
// grid 2048, block 256 (4 waves). Per wave: 4 tiles of 16 consecutive flat
// positions; per tile: stage LN'd x bf16 (double-buffered, per-wave LDS),
// GEMM1 (x@Wg) -> sigmoid gate -> y -> GEMM2 (y@Wo) -> store.
__global__ __launch_bounds__(256) void k3_kernel(
    const float* __restrict__ msa, const float* __restrict__ lnw,
    const float* __restrict__ lnb, const float* __restrict__ Wg,
    const float* __restrict__ bg, const float* __restrict__ Wo,
    const float* __restrict__ bo, const float* __restrict__ wsAttn,
    float* __restrict__ outp)
{
  __shared__ unsigned short wgT[64][64];        // 8 KB
  __shared__ unsigned short woT[64][64];        // 8 KB
  __shared__ unsigned short xt[4][2][16][64];   // 16 KB
  __shared__ unsigned short yt[4][16][64];      // 8 KB

  const int tid  = threadIdx.x;
  const int w    = tid >> 6;
  const int lane = tid & 63;

  {
    const int d  = tid & 63;
    const int jg = tid >> 6;
#pragma unroll
    for (int j0 = 0; j0 < 16; ++j0) {
      const int j  = (j0 << 2) + jg;
      const int gs = (((d >> 3) ^ (j & 7)) << 3) + (d & 7);
      wgT[j][gs] = f2bf(Wg[d * 64 + j]);
      woT[j][gs] = f2bf(Wo[d * 64 + j]);
    }
  }
  __syncthreads();

  const int c  = lane & 15;
  const int kg = lane >> 4;
  const int p  = lane >> 4;
  const int f  = lane & 15;

  bh8 bgf0[4], bgf1[4], bof0[4], bof1[4];
  float bgv[4], bov[4];
#pragma unroll
  for (int nt = 0; nt < 4; ++nt) {
    const int col = (nt << 4) + c;
    const int sw  = col & 7;
    bgf0[nt] = *(const bh8*)&wgT[col][((kg    ) ^ sw) << 3];
    bgf1[nt] = *(const bh8*)&wgT[col][((kg + 4) ^ sw) << 3];
    bof0[nt] = *(const bh8*)&woT[col][((kg    ) ^ sw) << 3];
    bof1[nt] = *(const bh8*)&woT[col][((kg + 4) ^ sw) << 3];
    bgv[nt] = bg[col];
    bov[nt] = bo[col];
  }

  const fx4 lwv = *(const fx4*)(lnw + 4 * f);
  const fx4 lbv = *(const fx4*)(lnb + 4 * f);
  const fx4 zero = {0.f, 0.f, 0.f, 0.f};

#pragma unroll
  for (int it = 0; it < 4; ++it) {
    const int Tg = (blockIdx.x << 4) + (w << 2) + it;
    const size_t pb = (size_t)Tg << 4;          // base flat position
    const int bufp = it & 1;
#pragma unroll
    for (int jq = 0; jq < 4; ++jq) {
      const int j = (jq << 2) + p;
      fx4 x = *(const fx4*)(msa + (pb + j) * 64 + 4 * f);
      float s  = x.x + x.y + x.z + x.w;
      float ss = x.x * x.x + x.y * x.y + x.z * x.z + x.w * x.w;
#pragma unroll
      for (int m = 1; m <= 8; m <<= 1) { s += __shfl_xor(s, m); ss += __shfl_xor(ss, m); }
      const float mu  = s * (1.f / 64.f);
      const float var = ss * (1.f / 64.f) - mu * mu;
      const float rs  = rsqrtf(var + 1e-5f);
      const float x0 = (x.x - mu) * rs * lwv.x + lbv.x;
      const float x1 = (x.y - mu) * rs * lwv.y + lbv.y;
      const float x2 = (x.z - mu) * rs * lwv.z + lbv.z;
      const float x3 = (x.w - mu) * rs * lwv.w + lbv.w;
      const unsigned int u0 = (unsigned int)f2bf(x0) | ((unsigned int)f2bf(x1) << 16);
      const unsigned int u1 = (unsigned int)f2bf(x2) | ((unsigned int)f2bf(x3) << 16);
      const int gsw = (((f >> 1) ^ (j & 7)) << 3) + ((f & 1) << 2);
      ux2 uu = {u0, u1};
      *(ux2*)&xt[w][bufp][j][gsw] = uu;
    }
    bh8 a0 = *(const bh8*)&xt[w][bufp][c][((kg    ) ^ (c & 7)) << 3];
    bh8 a1 = *(const bh8*)&xt[w][bufp][c][((kg + 4) ^ (c & 7)) << 3];
    fx4 ag[4];
#pragma unroll
    for (int nt = 0; nt < 4; ++nt) {
      fx4 t = __builtin_amdgcn_mfma_f32_16x16x32_bf16(a0, bgf0[nt], zero, 0, 0, 0);
      ag[nt] = __builtin_amdgcn_mfma_f32_16x16x32_bf16(a1, bgf1[nt], t, 0, 0, 0);
    }
    const int lb2 = (int)(pb & (LL - 1));
#pragma unroll
    for (int nt = 0; nt < 4; ++nt) {
      const int col = (nt << 4) + c;
#pragma unroll
      for (int r = 0; r < 4; ++r) {
        const int rloc = (kg << 2) + r;
        const float z  = ag[nt][r] + bgv[nt];
        const float gt = 1.f / (1.f + __expf(-z));
        const float av = wsAttn[(lb2 + rloc) * 64 + col];
        const float y  = gt * av;
        const int gy = (((col >> 3) ^ (rloc & 7)) << 3) + (col & 7);
        yt[w][rloc][gy] = f2bf(y);
      }
    }
    bh8 y0 = *(const bh8*)&yt[w][c][((kg    ) ^ (c & 7)) << 3];
    bh8 y1 = *(const bh8*)&yt[w][c][((kg + 4) ^ (c & 7)) << 3];
    fx4 ao[4];
#pragma unroll
    for (int nt = 0; nt < 4; ++nt) {
      fx4 t = __builtin_amdgcn_mfma_f32_16x16x32_bf16(y0, bof0[nt], zero, 0, 0, 0);
      ao[nt] = __builtin_amdgcn_mfma_f32_16x16x32_bf16(y1, bof1[nt], t, 0, 0, 0);
    }
#pragma unroll
    for (int nt = 0; nt < 4; ++nt) {
      const int col = (nt << 4) + c;
#pragma unroll
      for (int r = 0; r < 4; ++r) {
        const int rloc = (kg << 2) + r;
        outp[(pb + rloc) * 64 + col] = ao[nt][r] + bov[nt];
      }
    }
  }
}

// ---------------------------------------------------------------- launcher
extern "C" void kernel_launch(void* const* d_in, const int* in_sizes, int n_in,
                              void* d_out, int out_size, void* d_ws, size_t ws_size,
                              hipStream_t stream) {
  const float* msa = (const float*)d_in[0];
  const float* lnw = (const float*)d_in[1];
  const float* lnb = (const float*)d_in[2];
  const float* Wq  = (const float*)d_in[3];
  const float* Wk  = (const float*)d_in[4];
  const float* Wv  = (const float*)d_in[5];
  const float* Wg  = (const float*)d_in[6];
  const float* bg  = (const float*)d_in[7];
  const float* Wo  = (const float*)d_in[8];
  const float* bo  = (const float*)d_in[9];
  float* outp = (float*)d_out;

  char* ws = (char*)d_ws;
  unsigned short* wsKV    = (unsigned short*)ws;               // 16,777,216 B  [l][n][16]
  float*          wsXsumP = (float*)(ws + 16777216);           //  8,388,608 B  [32][l][64]
  float*          wsAttn  = (float*)(ws + 25165824);           //    262,144 B  [l][64]

  k1_kernel<<<dim3(2048), dim3(256), 0, stream>>>(msa, lnw, lnb, Wk, Wv, wsKV, wsXsumP);
  k2_kernel<<<dim3(1024), dim3(512), 0, stream>>>(Wq, wsXsumP, wsKV, wsAttn);
  k3_kernel<<<dim3(2048), dim3(256), 0, stream>>>(msa, lnw, lnb, Wg, bg, Wo, bo, wsAttn, outp);
}